// Round 5
// baseline (1054.805 us; speedup 1.0000x reference)
//
#include <hip/hip_runtime.h>
#include <stdint.h>

#define NNODES 50000
#define NEDGES 800000
#define CDIM   64
#define SHD    9
#define EBD    16

using f32x4  = __attribute__((ext_vector_type(4))) float;
using bf16x8 = __attribute__((ext_vector_type(8))) __bf16;

static __device__ __forceinline__ unsigned short bfr(float x) {
  union { __bf16 b; unsigned short u; } t;
  t.b = (__bf16)x;            // native cvt, RNE (compiler emits cvt_pk pairs)
  return t.u;
}
static __device__ __forceinline__ float bf2f(unsigned short b) {
  union { unsigned u; float f; } v; v.u = ((unsigned)b) << 16;
  return v.f;
}
static __device__ __forceinline__ f32x4 mfma16(bf16x8 a, bf16x8 b, f32x4 c) {
  return __builtin_amdgcn_mfma_f32_16x16x32_bf16(a, b, c, 0, 0, 0);
}
static __device__ __forceinline__ ushort4 cvt4(float4 v) {
  return make_ushort4(bfr(v.x), bfr(v.y), bfr(v.z), bfr(v.w));
}
static __device__ __forceinline__ bf16x8 pack8(float4 a, float4 b) {
  union { unsigned short u[8]; bf16x8 v; } t;
  t.u[0]=bfr(a.x); t.u[1]=bfr(a.y); t.u[2]=bfr(a.z); t.u[3]=bfr(a.w);
  t.u[4]=bfr(b.x); t.u[5]=bfr(b.y); t.u[6]=bfr(b.z); t.u[7]=bfr(b.w);
  return t.v;
}
static __device__ __forceinline__ bf16x8 ldA(const unsigned short* __restrict__ p, int idx) {
  union { uint4 q; bf16x8 v; } t;
  t.q = reinterpret_cast<const uint4*>(p)[idx];
  return t.v;
}
static __device__ __forceinline__ bf16x8 ldL(const unsigned short* p) {
  union { uint4 q; bf16x8 v; } t;
  t.q = *reinterpret_cast<const uint4*>(p);
  return t.v;
}
static __device__ __forceinline__ float4 relu4(float4 v) {
  v.x = v.x > 0.f ? v.x : 0.f; v.y = v.y > 0.f ? v.y : 0.f;
  v.z = v.z > 0.f ? v.z : 0.f; v.w = v.w > 0.f ? v.w : 0.f;
  return v;
}
// XOR-swizzled LDS indices (short units). act stride 128 shorts (256B),
// vt stride 64 shorts (128B). Swizzle flips 16B units within 128B stripes:
// preserves 8B/16B alignment, spreads 16-row b128 frag reads over all banks.
static __device__ __forceinline__ int aidx(int r, int c) {
  return (r * 128 + c) ^ ((r & 7) << 3);
}
static __device__ __forceinline__ int vidx(int r, int c) {
  return (r * 64 + c) ^ ((r & 7) << 3);
}

// Pack fp32 w[K][N] -> bf16 fragment order (works as A- or B-operand):
// dst[((nt*KS+ks)*64+lane)*8+j] = w[rowmap(ks*32+(lane>>4)*8+j)][nt*16+(lane&15)]
// mode 1 (w_tp): vt col space [v16|fe9|z3|fes16|z20] -> w rows {c, c-7, c-10}.
__global__ void pack_all_kernel(
    const float* __restrict__ wev1, const float* __restrict__ weu1,
    const float* __restrict__ wnl1, const float* __restrict__ weu2,
    const float* __restrict__ wnl2, const float* __restrict__ wev2,
    const float* __restrict__ wtp,
    unsigned short* __restrict__ pev1, unsigned short* __restrict__ peu1,
    unsigned short* __restrict__ pnl1, unsigned short* __restrict__ peu2,
    unsigned short* __restrict__ pnl2, unsigned short* __restrict__ pev2,
    unsigned short* __restrict__ ptp) {
  int b = blockIdx.x;
  const float* w; unsigned short* dst; int K, N, KS, NT, base, mode = 0;
  if (b < 24)      { w = wev1; dst = pev1; K = 192; N = 256; KS = 6; NT = 16; base = 0; }
  else if (b < 48) { w = weu1; dst = peu1; K = 192; N = 256; KS = 6; NT = 16; base = 24; }
  else if (b < 64) { w = wnl1; dst = pnl1; K = 128; N = 256; KS = 4; NT = 16; base = 48; }
  else if (b < 72) { w = weu2; dst = peu2; K = 256; N = 64;  KS = 8; NT = 4;  base = 64; }
  else if (b < 80) { w = wnl2; dst = pnl2; K = 256; N = 64;  KS = 8; NT = 4;  base = 72; }
  else if (b < 82) { w = wev2; dst = pev2; K = 256; N = 9;   KS = 8; NT = 1;  base = 80; }
  else             { w = wtp;  dst = ptp;  K = 44;  N = 64;  KS = 2; NT = 4;  base = 82; mode = 1; }
  int idx = (b - base) * 256 + threadIdx.x;
  int total = NT * KS * 64;
  if (idx >= total) return;
  int lane = idx & 63;
  int t = idx >> 6;
  int ks = t % KS;
  int nt = t / KS;
  int n  = nt * 16 + (lane & 15);
  int kb = ks * 32 + ((lane >> 4) << 3);
  unsigned short v[8];
#pragma unroll
  for (int jj = 0; jj < 8; ++jj) {
    int k = kb + jj;
    int rm;
    if (mode == 0) rm = (k < K) ? k : -1;
    else rm = (k < 9) ? k : (k >= 16 && k <= 24) ? k - 7 : (k >= 28 && k <= 43) ? k - 10 : -1;
    float val = (rm >= 0 && n < N) ? w[(size_t)rm * N + n] : 0.f;
    v[jj] = bfr(val);
  }
  uint4 pk;
  pk.x = (unsigned)v[0] | ((unsigned)v[1] << 16);
  pk.y = (unsigned)v[2] | ((unsigned)v[3] << 16);
  pk.z = (unsigned)v[4] | ((unsigned)v[5] << 16);
  pk.w = (unsigned)v[6] | ((unsigned)v[7] << 16);
  reinterpret_cast<uint4*>(dst)[idx] = pk;
}

// 128 edges/block, 4 waves. Wave = (we=wid&1 edge-half, wm=wid>>1 m-half).
// Big GEMMs: weights as A (m-quarter per wave per half), x^T as persistent
// B-frags for the wave's 4 edge-groups (4 MFMA per weight load).
// Small GEMMs + epilogue: wave owns edges wid*32..wid*32+31 (groups 2wid,2wid+1).
// C layout everywhere: col=lane&15 (edge), row=(lane>>4)*4+reg (feature).
__global__ __launch_bounds__(256, 3) void edge_kernel(
    const float* __restrict__ hn, const float* __restrict__ he,
    const float* __restrict__ fe, const float* __restrict__ fes,
    const float* __restrict__ nrm,
    const int* __restrict__ esrc, const int* __restrict__ edst,
    const unsigned short* __restrict__ pev1, const float* __restrict__ bev1,
    const unsigned short* __restrict__ pev2, const float* __restrict__ bev2,
    const unsigned short* __restrict__ ptp,  const float* __restrict__ btp,
    const unsigned short* __restrict__ peu1, const float* __restrict__ beu1,
    const unsigned short* __restrict__ peu2, const float* __restrict__ beu2,
    float* __restrict__ out_he, float* __restrict__ nf) {
  __shared__ unsigned short act[128 * 128];  // staged hs|hd, then activation halves (swz)
  __shared__ unsigned short vt[128 * 64];    // [v16|fe9|z3|fes16|z20] -> t (swz)

  const int tid  = threadIdx.x;
  const int lane = tid & 63;
  const int wid  = tid >> 6;
  const int e    = lane & 15;
  const int j    = lane >> 4;
  const int koff = j << 3;
  const int we   = wid & 1;
  const int wm   = wid >> 1;
  const int E0   = blockIdx.x * 128;

  // ---- P0 staging: 2 threads/edge; q=0 -> hs + vt[0..31], q=1 -> hd + vt[32..63] ----
  {
    const int e2  = tid >> 1;
    const int q   = tid & 1;
    const int eg2 = E0 + e2;
    const int nidx = q ? edst[eg2] : esrc[eg2];
    const float4* hp = reinterpret_cast<const float4*>(hn + (size_t)nidx * 64);
#pragma unroll
    for (int i = 0; i < 16; ++i)
      *reinterpret_cast<ushort4*>(&act[aidx(e2, q * 64 + i * 4)]) = cvt4(hp[i]);
    ushort4 z = make_ushort4(0, 0, 0, 0);
    if (q == 0) {
#pragma unroll
      for (int i = 0; i < 4; ++i)
        *reinterpret_cast<ushort4*>(&vt[vidx(e2, i * 4)]) = z;   // v slots 0..15
      const float* fp = fe + (size_t)eg2 * SHD;
      *reinterpret_cast<ushort4*>(&vt[vidx(e2, 16)]) =
          make_ushort4(bfr(fp[0]), bfr(fp[1]), bfr(fp[2]), bfr(fp[3]));
      *reinterpret_cast<ushort4*>(&vt[vidx(e2, 20)]) =
          make_ushort4(bfr(fp[4]), bfr(fp[5]), bfr(fp[6]), bfr(fp[7]));
      *reinterpret_cast<ushort4*>(&vt[vidx(e2, 24)]) =
          make_ushort4(bfr(fp[8]), 0, 0, 0);                      // fe8 + zeros
      float4 fs0 = *reinterpret_cast<const float4*>(fes + (size_t)eg2 * EBD);
      *reinterpret_cast<ushort4*>(&vt[vidx(e2, 28)]) = cvt4(fs0);
    } else {
      const float4* fsp = reinterpret_cast<const float4*>(fes + (size_t)eg2 * EBD);
      *reinterpret_cast<ushort4*>(&vt[vidx(e2, 32)]) = cvt4(fsp[1]);
      *reinterpret_cast<ushort4*>(&vt[vidx(e2, 36)]) = cvt4(fsp[2]);
      *reinterpret_cast<ushort4*>(&vt[vidx(e2, 40)]) = cvt4(fsp[3]);
#pragma unroll
      for (int i = 0; i < 5; ++i)
        *reinterpret_cast<ushort4*>(&vt[vidx(e2, 44 + i * 4)]) = z;
    }
  }
  __syncthreads();  // B1

  // ---- P1: persistent B-frags for this wave's 4 edge-groups ----
  bf16x8 bhe[4][2];   // he feats 0..63 (from global), dead after GEMM1
  bf16x8 bhh[4][4];   // hs|hd feats 64..191 (from staged act), live through GEMM3
#pragma unroll
  for (int gl = 0; gl < 4; ++gl) {
    const int rowg = (we * 4 + gl) * 16 + e;
    const float4* hp = reinterpret_cast<const float4*>(he + (size_t)(E0 + rowg) * 64);
#pragma unroll
    for (int s = 0; s < 2; ++s)
      bhe[gl][s] = pack8(hp[s * 8 + j * 2], hp[s * 8 + j * 2 + 1]);
#pragma unroll
    for (int s = 0; s < 4; ++s)
      bhh[gl][s] = ldL(&act[aidx(rowg, s * 32 + koff)]);
  }
  __syncthreads();  // B2 (all frag reads done before act is overwritten)

  // ---- GEMM1 (a1^T halves) fused with GEMM2 (v partial-K, own edges) ----
  f32x4 accv[2];
  {
    f32x4 vi = (f32x4){0.f, 0.f, 0.f, 0.f};
    if (j < 2) {
      float4 t = *reinterpret_cast<const float4*>(bev2 + j * 4);
      vi[0] = t.x; vi[1] = t.y; vi[2] = t.z; vi[3] = t.w;
    } else if (j == 2) vi[0] = bev2[8];
    accv[0] = vi; accv[1] = vi;
  }
#pragma unroll
  for (int h = 0; h < 2; ++h) {
#pragma unroll
    for (int ml = 0; ml < 4; ++ml) {
      const int mt = h * 8 + wm * 4 + ml;
      float4 bs = *reinterpret_cast<const float4*>(bev1 + mt * 16 + j * 4);
      f32x4 c[4];
#pragma unroll
      for (int gl = 0; gl < 4; ++gl) { c[gl][0] = bs.x; c[gl][1] = bs.y; c[gl][2] = bs.z; c[gl][3] = bs.w; }
#pragma unroll
      for (int s = 0; s < 6; ++s) {
        bf16x8 a = ldA(pev1, (mt * 6 + s) * 64 + lane);
#pragma unroll
        for (int gl = 0; gl < 4; ++gl)
          c[gl] = mfma16(a, (s < 2) ? bhe[gl][s] : bhh[gl][s - 2], c[gl]);
      }
      const int colh = (wm * 4 + ml) * 16 + j * 4;
#pragma unroll
      for (int gl = 0; gl < 4; ++gl) {
        float4 v = relu4(make_float4(c[gl][0], c[gl][1], c[gl][2], c[gl][3]));
        *reinterpret_cast<ushort4*>(&act[aidx((we * 4 + gl) * 16 + e, colh)]) = cvt4(v);
      }
    }
    __syncthreads();  // half ready
#pragma unroll
    for (int ksl = 0; ksl < 4; ++ksl) {
      bf16x8 aw = ldA(pev2, (h * 4 + ksl) * 64 + lane);
#pragma unroll
      for (int gi = 0; gi < 2; ++gi) {
        bf16x8 b = ldL(&act[aidx((2 * wid + gi) * 16 + e, ksl * 32 + koff)]);
        accv[gi] = mfma16(aw, b, accv[gi]);
      }
    }
    if (h == 0) __syncthreads();  // readers done before half-1 overwrites
  }

  // ---- v -> vt (cols >=9 are exact zeros via zero-padded pack + zero bias) ----
#pragma unroll
  for (int gi = 0; gi < 2; ++gi) {
    const int row = (2 * wid + gi) * 16 + e;
    *reinterpret_cast<ushort4*>(&vt[vidx(row, j * 4)]) =
        cvt4(make_float4(accv[gi][0], accv[gi][1], accv[gi][2], accv[gi][3]));
  }
  // ---- GEMM_t: t^T = w_tp^T @ [v|fe|fes]^T (K=64), own edges, within-wave ----
  {
    bf16x8 awt[8];
#pragma unroll
    for (int s8 = 0; s8 < 8; ++s8) awt[s8] = ldA(ptp, s8 * 64 + lane);
#pragma unroll
    for (int gi = 0; gi < 2; ++gi) {
      const int row = (2 * wid + gi) * 16 + e;
      bf16x8 b0 = ldL(&vt[vidx(row, koff)]);
      bf16x8 b1 = ldL(&vt[vidx(row, 32 + koff)]);
      f32x4 ct[4];
#pragma unroll
      for (int m2 = 0; m2 < 4; ++m2) {
        float4 bs = *reinterpret_cast<const float4*>(btp + m2 * 16 + j * 4);
        ct[m2][0] = bs.x; ct[m2][1] = bs.y; ct[m2][2] = bs.z; ct[m2][3] = bs.w;
        ct[m2] = mfma16(awt[m2 * 2], b0, ct[m2]);
        ct[m2] = mfma16(awt[m2 * 2 + 1], b1, ct[m2]);
      }
#pragma unroll
      for (int m2 = 0; m2 < 4; ++m2)
        *reinterpret_cast<ushort4*>(&vt[vidx(row, m2 * 16 + j * 4)]) =
            cvt4(make_float4(ct[m2][0], ct[m2][1], ct[m2][2], ct[m2][3]));
    }
  }
  __syncthreads();  // B6: t visible cross-wave

  // ---- GEMM3 (a2^T halves) fused with GEMM4 (he delta partial-K, own edges) ----
  bf16x8 bt[4][2];
#pragma unroll
  for (int gl = 0; gl < 4; ++gl) {
    const int rowg = (we * 4 + gl) * 16 + e;
    bt[gl][0] = ldL(&vt[vidx(rowg, koff)]);
    bt[gl][1] = ldL(&vt[vidx(rowg, 32 + koff)]);
  }
  f32x4 acc4[2][4];
#pragma unroll
  for (int mo = 0; mo < 4; ++mo) {
    float4 bs = *reinterpret_cast<const float4*>(beu2 + mo * 16 + j * 4);
    acc4[0][mo][0] = bs.x; acc4[0][mo][1] = bs.y; acc4[0][mo][2] = bs.z; acc4[0][mo][3] = bs.w;
    acc4[1][mo] = acc4[0][mo];
  }
#pragma unroll
  for (int h = 0; h < 2; ++h) {
#pragma unroll
    for (int ml = 0; ml < 4; ++ml) {
      const int mt = h * 8 + wm * 4 + ml;
      float4 bs = *reinterpret_cast<const float4*>(beu1 + mt * 16 + j * 4);
      f32x4 c[4];
#pragma unroll
      for (int gl = 0; gl < 4; ++gl) { c[gl][0] = bs.x; c[gl][1] = bs.y; c[gl][2] = bs.z; c[gl][3] = bs.w; }
#pragma unroll
      for (int s = 0; s < 6; ++s) {
        bf16x8 a = ldA(peu1, (mt * 6 + s) * 64 + lane);
#pragma unroll
        for (int gl = 0; gl < 4; ++gl)
          c[gl] = mfma16(a, (s < 2) ? bt[gl][s] : bhh[gl][s - 2], c[gl]);
      }
      const int colh = (wm * 4 + ml) * 16 + j * 4;
#pragma unroll
      for (int gl = 0; gl < 4; ++gl) {
        float4 v = relu4(make_float4(c[gl][0], c[gl][1], c[gl][2], c[gl][3]));
        *reinterpret_cast<ushort4*>(&act[aidx((we * 4 + gl) * 16 + e, colh)]) = cvt4(v);
      }
    }
    __syncthreads();
#pragma unroll
    for (int ksl = 0; ksl < 4; ++ksl) {
      bf16x8 b0 = ldL(&act[aidx((2 * wid + 0) * 16 + e, ksl * 32 + koff)]);
      bf16x8 b1 = ldL(&act[aidx((2 * wid + 1) * 16 + e, ksl * 32 + koff)]);
#pragma unroll
      for (int mo = 0; mo < 4; ++mo) {
        bf16x8 a = ldA(peu2, (mo * 8 + h * 4 + ksl) * 64 + lane);
        acc4[0][mo] = mfma16(a, b0, acc4[0][mo]);
        acc4[1][mo] = mfma16(a, b1, acc4[1][mo]);
      }
    }
    if (h == 0) __syncthreads();
  }

  // ---- epilogue: he_new = he + delta (bias folded); store + atomic scatter ----
#pragma unroll
  for (int gi = 0; gi < 2; ++gi) {
    const int eg = E0 + (2 * wid + gi) * 16 + e;
    const float nv = nrm[eg];
    const int dn = edst[eg];
#pragma unroll
    for (int mo = 0; mo < 4; ++mo) {
      float4 h4 = *reinterpret_cast<const float4*>(he + (size_t)eg * 64 + mo * 16 + j * 4);
      float4 vout = make_float4(acc4[gi][mo][0] + h4.x, acc4[gi][mo][1] + h4.y,
                                acc4[gi][mo][2] + h4.z, acc4[gi][mo][3] + h4.w);
      *reinterpret_cast<float4*>(out_he + (size_t)eg * 64 + mo * 16 + j * 4) = vout;
      float* nfp = nf + (size_t)dn * 64 + mo * 16 + j * 4;
      atomicAdd(nfp + 0, vout.x * nv);
      atomicAdd(nfp + 1, vout.y * nv);
      atomicAdd(nfp + 2, vout.z * nv);
      atomicAdd(nfp + 3, vout.w * nv);
    }
  }
}

// Node MLP: hn_new = hn + relu([hn|node_ftr]@w_nl1+b)@w_nl2+b  (proven R2/R4 version)
__global__ __launch_bounds__(256, 3) void node_kernel(
    const float* __restrict__ hn, const float* __restrict__ nf,
    const unsigned short* __restrict__ pnl1, const float* __restrict__ bnl1,
    const unsigned short* __restrict__ pnl2, const float* __restrict__ bnl2,
    float* __restrict__ out) {
  __shared__ unsigned short xn[64][136];
  __shared__ unsigned short act[64][264];
  const int tid = threadIdx.x, lane = tid & 63, wid = tid >> 6;
  const int nb = blockIdx.x * 64;
  const int arow = lane & 15, koff = (lane >> 4) << 3, r0 = (lane >> 4) << 2;
  {
    const int rrow = tid >> 2, q = tid & 3, cg = q << 4;
    const int gidx = nb + rrow;
    if (gidx < NNODES) {
      const float4* aP = reinterpret_cast<const float4*>(hn + (size_t)gidx * 64 + cg);
      const float4* bP = reinterpret_cast<const float4*>(nf + (size_t)gidx * 64 + cg);
#pragma unroll
      for (int i = 0; i < 4; ++i) {
        float4 a = aP[i], b = bP[i];
        *reinterpret_cast<ushort4*>(&xn[rrow][cg + i * 4])      = cvt4(a);
        *reinterpret_cast<ushort4*>(&xn[rrow][64 + cg + i * 4]) = cvt4(b);
      }
    } else {
      ushort4 z = make_ushort4(0, 0, 0, 0);
#pragma unroll
      for (int i = 0; i < 4; ++i) {
        *reinterpret_cast<ushort4*>(&xn[rrow][cg + i * 4]) = z;
        *reinterpret_cast<ushort4*>(&xn[rrow][64 + cg + i * 4]) = z;
      }
    }
  }
  __syncthreads();
  {
    f32x4 acc[4][4];
#pragma unroll
    for (int m = 0; m < 4; ++m)
#pragma unroll
      for (int n = 0; n < 4; ++n) acc[m][n] = (f32x4){0.f, 0.f, 0.f, 0.f};
#pragma unroll
    for (int ks = 0; ks < 4; ++ks) {
      bf16x8 a[4];
#pragma unroll
      for (int m = 0; m < 4; ++m)
        a[m] = ldL(&xn[m * 16 + arow][ks * 32 + koff]);
#pragma unroll
      for (int n = 0; n < 4; ++n) {
        bf16x8 b = ldA(pnl1, ((wid * 4 + n) * 4 + ks) * 64 + lane);
#pragma unroll
        for (int m = 0; m < 4; ++m) acc[m][n] = mfma16(a[m], b, acc[m][n]);
      }
    }
#pragma unroll
    for (int n = 0; n < 4; ++n) {
      const int col = wid * 64 + n * 16 + arow;
      const float bias = bnl1[col];
#pragma unroll
      for (int m = 0; m < 4; ++m)
#pragma unroll
        for (int r = 0; r < 4; ++r) {
          float v = acc[m][n][r] + bias;
          act[m * 16 + r0 + r][col] = bfr(v > 0.f ? v : 0.f);
        }
    }
  }
  __syncthreads();
  {
    f32x4 acc[4];
#pragma unroll
    for (int n = 0; n < 4; ++n) acc[n] = (f32x4){0.f, 0.f, 0.f, 0.f};
    const int mrow = wid * 16 + arow;
#pragma unroll
    for (int ks = 0; ks < 8; ++ks) {
      bf16x8 a = ldL(&act[mrow][ks * 32 + koff]);
#pragma unroll
      for (int n = 0; n < 4; ++n) {
        bf16x8 b = ldA(pnl2, (n * 8 + ks) * 64 + lane);
        acc[n] = mfma16(a, b, acc[n]);
      }
    }
#pragma unroll
    for (int r = 0; r < 4; ++r) {
      const int row = wid * 16 + r0 + r;
      const int gidx = nb + row;
      if (gidx < NNODES) {
#pragma unroll
        for (int n = 0; n < 4; ++n) {
          const int col = n * 16 + arow;
          out[(size_t)gidx * 64 + col] = bf2f(xn[row][col]) + acc[n][r] + bnl2[col];
        }
      }
    }
  }
}

extern "C" void kernel_launch(void* const* d_in, const int* in_sizes, int n_in,
                              void* d_out, int out_size, void* d_ws, size_t ws_size,
                              hipStream_t stream) {
  const float* hn   = (const float*)d_in[0];
  const float* he   = (const float*)d_in[1];
  const float* fe   = (const float*)d_in[2];
  const float* fes  = (const float*)d_in[3];
  const float* nrm  = (const float*)d_in[4];
  const int*   esrc = (const int*)d_in[5];
  const int*   edst = (const int*)d_in[6];
  const float* w_ev1 = (const float*)d_in[7];  const float* b_ev1 = (const float*)d_in[8];
  const float* w_ev2 = (const float*)d_in[9];  const float* b_ev2 = (const float*)d_in[10];
  const float* w_tp  = (const float*)d_in[11]; const float* b_tp  = (const float*)d_in[12];
  const float* w_eu1 = (const float*)d_in[13]; const float* b_eu1 = (const float*)d_in[14];
  const float* w_eu2 = (const float*)d_in[15]; const float* b_eu2 = (const float*)d_in[16];
  const float* w_nl1 = (const float*)d_in[17]; const float* b_nl1 = (const float*)d_in[18];
  const float* w_nl2 = (const float*)d_in[19]; const float* b_nl2 = (const float*)d_in[20];

  float* out = (float*)d_out;
  char* ws = (char*)d_ws;
  float* nfp = (float*)ws;
  size_t off = (size_t)NNODES * CDIM * sizeof(float);
  unsigned short* pev1 = (unsigned short*)(ws + off); off += (size_t)16 * 6 * 512 * 2;
  unsigned short* peu1 = (unsigned short*)(ws + off); off += (size_t)16 * 6 * 512 * 2;
  unsigned short* pev2 = (unsigned short*)(ws + off); off += (size_t)1 * 8 * 512 * 2;
  unsigned short* peu2 = (unsigned short*)(ws + off); off += (size_t)4 * 8 * 512 * 2;
  unsigned short* ptp  = (unsigned short*)(ws + off); off += (size_t)4 * 2 * 512 * 2;
  unsigned short* pnl1 = (unsigned short*)(ws + off); off += (size_t)16 * 4 * 512 * 2;
  unsigned short* pnl2 = (unsigned short*)(ws + off); off += (size_t)4 * 8 * 512 * 2;

  hipMemsetAsync(nfp, 0, (size_t)NNODES * CDIM * sizeof(float), stream);

  pack_all_kernel<<<84, 256, 0, stream>>>(
      w_ev1, w_eu1, w_nl1, w_eu2, w_nl2, w_ev2, w_tp,
      pev1, peu1, pnl1, peu2, pnl2, pev2, ptp);

  edge_kernel<<<NEDGES / 128, 256, 0, stream>>>(
      hn, he, fe, fes, nrm, esrc, edst,
      pev1, b_ev1, pev2, b_ev2, ptp, b_tp, peu1, b_eu1, peu2, b_eu2,
      out + (size_t)NNODES * CDIM, nfp);

  node_kernel<<<(NNODES + 63) / 64, 256, 0, stream>>>(
      hn, nfp, pnl1, b_nl1, pnl2, b_nl2, out);
}

// Round 6
// 667.425 us; speedup vs baseline: 1.5804x; 1.5804x over previous
//
#include <hip/hip_runtime.h>
#include <stdint.h>

#define NNODES 50000
#define NEDGES 800000
#define CDIM   64
#define SHD    9
#define EBD    16

using f32x4  = __attribute__((ext_vector_type(4))) float;
using bf16x8 = __attribute__((ext_vector_type(8))) __bf16;

static __device__ __forceinline__ unsigned short bfr(float x) {
  union { __bf16 b; unsigned short u; } t;
  t.b = (__bf16)x;            // native cvt, RNE
  return t.u;
}
static __device__ __forceinline__ float bf2f(unsigned short b) {
  union { unsigned u; float f; } v; v.u = ((unsigned)b) << 16;
  return v.f;
}
static __device__ __forceinline__ f32x4 mfma16(bf16x8 a, bf16x8 b, f32x4 c) {
  return __builtin_amdgcn_mfma_f32_16x16x32_bf16(a, b, c, 0, 0, 0);
}
static __device__ __forceinline__ ushort4 cvt4(float4 v) {
  return make_ushort4(bfr(v.x), bfr(v.y), bfr(v.z), bfr(v.w));
}
static __device__ __forceinline__ bf16x8 ldA(const unsigned short* __restrict__ p, int idx) {
  union { uint4 q; bf16x8 v; } t;
  t.q = reinterpret_cast<const uint4*>(p)[idx];
  return t.v;
}
static __device__ __forceinline__ bf16x8 ldL(const unsigned short* p) {
  union { uint4 q; bf16x8 v; } t;
  t.q = *reinterpret_cast<const uint4*>(p);
  return t.v;
}
static __device__ __forceinline__ float4 relu4(float4 v) {
  v.x = v.x > 0.f ? v.x : 0.f; v.y = v.y > 0.f ? v.y : 0.f;
  v.z = v.z > 0.f ? v.z : 0.f; v.w = v.w > 0.f ? v.w : 0.f;
  return v;
}

// Pack fp32 w[K][N] -> bf16 fragment order (works as A- or B-operand):
// dst[((nt*KS+ks)*64+lane)*8+j] = w[rowmap(ks*32+(lane>>4)*8+j)][nt*16+(lane&15)]
// mode 1 (w_tp): vt col space [v16|fe9|z3|fes16|z20] -> w rows {c, c-7, c-10}.
__global__ void pack_all_kernel(
    const float* __restrict__ wev1, const float* __restrict__ weu1,
    const float* __restrict__ wnl1, const float* __restrict__ weu2,
    const float* __restrict__ wnl2, const float* __restrict__ wev2,
    const float* __restrict__ wtp,
    unsigned short* __restrict__ pev1, unsigned short* __restrict__ peu1,
    unsigned short* __restrict__ pnl1, unsigned short* __restrict__ peu2,
    unsigned short* __restrict__ pnl2, unsigned short* __restrict__ pev2,
    unsigned short* __restrict__ ptp) {
  int b = blockIdx.x;
  const float* w; unsigned short* dst; int K, N, KS, NT, base, mode = 0;
  if (b < 24)      { w = wev1; dst = pev1; K = 192; N = 256; KS = 6; NT = 16; base = 0; }
  else if (b < 48) { w = weu1; dst = peu1; K = 192; N = 256; KS = 6; NT = 16; base = 24; }
  else if (b < 64) { w = wnl1; dst = pnl1; K = 128; N = 256; KS = 4; NT = 16; base = 48; }
  else if (b < 72) { w = weu2; dst = peu2; K = 256; N = 64;  KS = 8; NT = 4;  base = 64; }
  else if (b < 80) { w = wnl2; dst = pnl2; K = 256; N = 64;  KS = 8; NT = 4;  base = 72; }
  else if (b < 82) { w = wev2; dst = pev2; K = 256; N = 9;   KS = 8; NT = 1;  base = 80; }
  else             { w = wtp;  dst = ptp;  K = 34;  N = 64;  KS = 2; NT = 4;  base = 82; mode = 1; }
  int idx = (b - base) * 256 + threadIdx.x;
  int total = NT * KS * 64;
  if (idx >= total) return;
  int lane = idx & 63;
  int t = idx >> 6;
  int ks = t % KS;
  int nt = t / KS;
  int n  = nt * 16 + (lane & 15);
  int kb = ks * 32 + ((lane >> 4) << 3);
  unsigned short v[8];
#pragma unroll
  for (int jj = 0; jj < 8; ++jj) {
    int k = kb + jj;
    int rm;
    if (mode == 0) rm = (k < K) ? k : -1;
    else rm = (k < 9) ? k : (k >= 16 && k <= 24) ? k - 7 : (k >= 28 && k <= 43) ? k - 10 : -1;
    float val = (rm >= 0 && n < N) ? w[(size_t)rm * N + n] : 0.f;
    v[jj] = bfr(val);
  }
  uint4 pk;
  pk.x = (unsigned)v[0] | ((unsigned)v[1] << 16);
  pk.y = (unsigned)v[2] | ((unsigned)v[3] << 16);
  pk.z = (unsigned)v[4] | ((unsigned)v[5] << 16);
  pk.w = (unsigned)v[6] | ((unsigned)v[7] << 16);
  reinterpret_cast<uint4*>(dst)[idx] = pk;
}

// Hybrid-orientation edge pipeline. 64 edges/block, 4 waves.
// GEMM1/3 swapped (weights as A, m-tiles PARTITIONED across waves: each
// weight fragment loaded once per block, 4 MFMA per load); outputs stored
// as ushort4 along features. GEMM2/GEMM_t swapped per-wave (own 16 edges).
// GEMM4 non-swapped (R2-verified) -> coalesced epilogue stores + atomics.
__global__ __launch_bounds__(256, 3) void edge_kernel(
    const float* __restrict__ hn, const float* __restrict__ he,
    const float* __restrict__ fe, const float* __restrict__ fes,
    const float* __restrict__ nrm,
    const int* __restrict__ esrc, const int* __restrict__ edst,
    const unsigned short* __restrict__ pev1, const float* __restrict__ bev1,
    const unsigned short* __restrict__ pev2, const float* __restrict__ bev2,
    const unsigned short* __restrict__ ptp,  const float* __restrict__ btp,
    const unsigned short* __restrict__ peu1, const float* __restrict__ beu1,
    const unsigned short* __restrict__ peu2, const float* __restrict__ beu2,
    float* __restrict__ out_he, float* __restrict__ nf) {
  __shared__ unsigned short xa[64][200];   // [he|hs|hd] (stride 100 dw === 4 mod 32)
  __shared__ unsigned short act[64][136];  // activation half (stride 68 dw === 4 mod 32)
  __shared__ unsigned short vt[64][72];    // [v16|fe9|z3|fes16|z20] -> t (36 dw === 4)

  const int tid  = threadIdx.x;
  const int lane = tid & 63;
  const int wid  = tid >> 6;
  const int eb   = blockIdx.x * 64;
  const int e    = lane & 15;
  const int j    = lane >> 4;
  const int koff = j << 3;

  // ---- staging: thread stages edge tid>>2 (coalesced float4 + ushort4) ----
  {
    const int et = tid >> 2, q = tid & 3, cg = q << 4;
    const int ege = eb + et;
    const int src = esrc[ege], dst = edst[ege];
    const float4* heP = reinterpret_cast<const float4*>(he + (size_t)ege * 64 + cg);
    const float4* hsP = reinterpret_cast<const float4*>(hn + (size_t)src * 64 + cg);
    const float4* hdP = reinterpret_cast<const float4*>(hn + (size_t)dst * 64 + cg);
#pragma unroll
    for (int i = 0; i < 4; ++i) {
      *reinterpret_cast<ushort4*>(&xa[et][cg + i * 4])       = cvt4(heP[i]);
      *reinterpret_cast<ushort4*>(&xa[et][64 + cg + i * 4])  = cvt4(hsP[i]);
      *reinterpret_cast<ushort4*>(&xa[et][128 + cg + i * 4]) = cvt4(hdP[i]);
    }
    const ushort4 z = make_ushort4(0, 0, 0, 0);
    if (q == 0) {
      const float* fp = fe + (size_t)ege * SHD;
      *reinterpret_cast<ushort4*>(&vt[et][16]) =
          make_ushort4(bfr(fp[0]), bfr(fp[1]), bfr(fp[2]), bfr(fp[3]));
      *reinterpret_cast<ushort4*>(&vt[et][20]) =
          make_ushort4(bfr(fp[4]), bfr(fp[5]), bfr(fp[6]), bfr(fp[7]));
    } else if (q == 1) {
      *reinterpret_cast<ushort4*>(&vt[et][24]) =
          make_ushort4(bfr(fe[(size_t)ege * SHD + 8]), 0, 0, 0);
      *reinterpret_cast<ushort4*>(&vt[et][44]) = z;
      *reinterpret_cast<ushort4*>(&vt[et][48]) = z;
    } else if (q == 2) {
      const float4* fsp = reinterpret_cast<const float4*>(fes + (size_t)ege * EBD);
      *reinterpret_cast<ushort4*>(&vt[et][28]) = cvt4(fsp[0]);
      *reinterpret_cast<ushort4*>(&vt[et][32]) = cvt4(fsp[1]);
      *reinterpret_cast<ushort4*>(&vt[et][52]) = z;
    } else {
      const float4* fsp = reinterpret_cast<const float4*>(fes + (size_t)ege * EBD);
      *reinterpret_cast<ushort4*>(&vt[et][36]) = cvt4(fsp[2]);
      *reinterpret_cast<ushort4*>(&vt[et][40]) = cvt4(fsp[3]);
      *reinterpret_cast<ushort4*>(&vt[et][56]) = z;
      *reinterpret_cast<ushort4*>(&vt[et][60]) = z;
    }
  }
  __syncthreads();  // S1

  // ---- persistent x^T B-frags (all 4 edge-groups, from LDS) ----
  bf16x8 bhe[4][2];   // he feats 0..63, dead after GEMM1
  bf16x8 bhh[4][4];   // hs|hd feats 64..191, live through GEMM3
#pragma unroll
  for (int gl = 0; gl < 4; ++gl) {
    const int row = gl * 16 + e;
    bhe[gl][0] = ldL(&xa[row][koff]);
    bhe[gl][1] = ldL(&xa[row][32 + koff]);
#pragma unroll
    for (int s = 0; s < 4; ++s) bhh[gl][s] = ldL(&xa[row][64 + s * 32 + koff]);
  }

  // ---- GEMM1 (swapped, m-tiles partitioned) + GEMM2 (swapped, own edges) ----
  f32x4 accv;
  {
    float4 vi = {0.f, 0.f, 0.f, 0.f};
    if (j < 2)       vi = *reinterpret_cast<const float4*>(bev2 + j * 4);
    else if (j == 2) vi.x = bev2[8];
    accv[0] = vi.x; accv[1] = vi.y; accv[2] = vi.z; accv[3] = vi.w;
  }
#pragma unroll
  for (int h = 0; h < 2; ++h) {
#pragma unroll
    for (int ml = 0; ml < 2; ++ml) {
      const int mt = h * 8 + wid * 2 + ml;
      float4 bs = *reinterpret_cast<const float4*>(bev1 + mt * 16 + j * 4);
      f32x4 c[4];
#pragma unroll
      for (int gl = 0; gl < 4; ++gl) { c[gl][0] = bs.x; c[gl][1] = bs.y; c[gl][2] = bs.z; c[gl][3] = bs.w; }
#pragma unroll
      for (int s = 0; s < 6; ++s) {
        bf16x8 a = ldA(pev1, (mt * 6 + s) * 64 + lane);
#pragma unroll
        for (int gl = 0; gl < 4; ++gl)
          c[gl] = mfma16(a, (s < 2) ? bhe[gl][s] : bhh[gl][s - 2], c[gl]);
      }
      const int colh = (wid * 2 + ml) * 16 + j * 4;
#pragma unroll
      for (int gl = 0; gl < 4; ++gl)
        *reinterpret_cast<ushort4*>(&act[gl * 16 + e][colh]) =
            cvt4(relu4(make_float4(c[gl][0], c[gl][1], c[gl][2], c[gl][3])));
    }
    __syncthreads();  // act half complete
#pragma unroll
    for (int ksl = 0; ksl < 4; ++ksl) {
      bf16x8 aw = ldA(pev2, (h * 4 + ksl) * 64 + lane);
      bf16x8 b  = ldL(&act[wid * 16 + e][ksl * 32 + koff]);
      accv = mfma16(aw, b, accv);
    }
    if (h == 0) __syncthreads();  // readers done before half-1 overwrites
  }

  // ---- v -> vt cols 0..15 (rows>=9 exact zeros via pack+bias); GEMM_t own edges ----
  *reinterpret_cast<ushort4*>(&vt[wid * 16 + e][j * 4]) =
      cvt4(make_float4(accv[0], accv[1], accv[2], accv[3]));
  {
    bf16x8 b0 = ldL(&vt[wid * 16 + e][koff]);
    bf16x8 b1 = ldL(&vt[wid * 16 + e][32 + koff]);
#pragma unroll
    for (int m2 = 0; m2 < 4; ++m2) {
      float4 bs = *reinterpret_cast<const float4*>(btp + m2 * 16 + j * 4);
      f32x4 ct; ct[0] = bs.x; ct[1] = bs.y; ct[2] = bs.z; ct[3] = bs.w;
      ct = mfma16(ldA(ptp, (m2 * 2 + 0) * 64 + lane), b0, ct);
      ct = mfma16(ldA(ptp, (m2 * 2 + 1) * 64 + lane), b1, ct);
      *reinterpret_cast<ushort4*>(&vt[wid * 16 + e][m2 * 16 + j * 4]) =
          cvt4(make_float4(ct[0], ct[1], ct[2], ct[3]));
    }
  }
  __syncthreads();  // S5: t visible cross-wave

  bf16x8 bt[4][2];
#pragma unroll
  for (int gl = 0; gl < 4; ++gl) {
    bt[gl][0] = ldL(&vt[gl * 16 + e][koff]);
    bt[gl][1] = ldL(&vt[gl * 16 + e][32 + koff]);
  }

  // ---- GEMM3 (swapped, partitioned) + GEMM4 (NON-swapped, own edges) ----
  f32x4 acc4[4];
#pragma unroll
  for (int n = 0; n < 4; ++n) {
    const float bz = beu2[n * 16 + e];            // col bias, same for all 4 rows
    acc4[n][0] = bz; acc4[n][1] = bz; acc4[n][2] = bz; acc4[n][3] = bz;
  }
#pragma unroll
  for (int h = 0; h < 2; ++h) {
#pragma unroll
    for (int ml = 0; ml < 2; ++ml) {
      const int mt = h * 8 + wid * 2 + ml;
      float4 bs = *reinterpret_cast<const float4*>(beu1 + mt * 16 + j * 4);
      f32x4 c[4];
#pragma unroll
      for (int gl = 0; gl < 4; ++gl) { c[gl][0] = bs.x; c[gl][1] = bs.y; c[gl][2] = bs.z; c[gl][3] = bs.w; }
#pragma unroll
      for (int s = 0; s < 6; ++s) {
        bf16x8 a = ldA(peu1, (mt * 6 + s) * 64 + lane);
#pragma unroll
        for (int gl = 0; gl < 4; ++gl)
          c[gl] = mfma16(a, (s < 2) ? bt[gl][s] : bhh[gl][s - 2], c[gl]);
      }
      const int colh = (wid * 2 + ml) * 16 + j * 4;
#pragma unroll
      for (int gl = 0; gl < 4; ++gl)
        *reinterpret_cast<ushort4*>(&act[gl * 16 + e][colh]) =
            cvt4(relu4(make_float4(c[gl][0], c[gl][1], c[gl][2], c[gl][3])));
    }
    __syncthreads();
#pragma unroll
    for (int ksl = 0; ksl < 4; ++ksl) {
      bf16x8 af = ldL(&act[wid * 16 + e][ksl * 32 + koff]);   // A-frag: row=edge, k contig
#pragma unroll
      for (int n = 0; n < 4; ++n) {
        bf16x8 bw = ldA(peu2, (n * 8 + h * 4 + ksl) * 64 + lane);
        acc4[n] = mfma16(af, bw, acc4[n]);
      }
    }
    if (h == 0) __syncthreads();
  }

  // ---- epilogue (R2-verified coalesced): C row = edge j*4+r, col = n*16+e ----
#pragma unroll
  for (int r = 0; r < 4; ++r) {
    const int erow = wid * 16 + j * 4 + r;
    const int eg = eb + erow;
    const float nv = nrm[eg];
    const int dn = edst[eg];
#pragma unroll
    for (int n = 0; n < 4; ++n) {
      const int col = n * 16 + e;
      float v = acc4[n][r] + bf2f(xa[erow][col]);
      out_he[(size_t)eg * 64 + col] = v;
      atomicAdd(nf + (size_t)dn * 64 + col, v * nv);
    }
  }
}

// Node MLP: hn_new = hn + relu([hn|node_ftr]@w_nl1+b)@w_nl2+b  (proven version)
__global__ __launch_bounds__(256, 3) void node_kernel(
    const float* __restrict__ hn, const float* __restrict__ nf,
    const unsigned short* __restrict__ pnl1, const float* __restrict__ bnl1,
    const unsigned short* __restrict__ pnl2, const float* __restrict__ bnl2,
    float* __restrict__ out) {
  __shared__ unsigned short xn[64][136];
  __shared__ unsigned short act[64][264];
  const int tid = threadIdx.x, lane = tid & 63, wid = tid >> 6;
  const int nb = blockIdx.x * 64;
  const int arow = lane & 15, koff = (lane >> 4) << 3, r0 = (lane >> 4) << 2;
  {
    const int rrow = tid >> 2, q = tid & 3, cg = q << 4;
    const int gidx = nb + rrow;
    if (gidx < NNODES) {
      const float4* aP = reinterpret_cast<const float4*>(hn + (size_t)gidx * 64 + cg);
      const float4* bP = reinterpret_cast<const float4*>(nf + (size_t)gidx * 64 + cg);
#pragma unroll
      for (int i = 0; i < 4; ++i) {
        float4 a = aP[i], b = bP[i];
        *reinterpret_cast<ushort4*>(&xn[rrow][cg + i * 4])      = cvt4(a);
        *reinterpret_cast<ushort4*>(&xn[rrow][64 + cg + i * 4]) = cvt4(b);
      }
    } else {
      ushort4 z = make_ushort4(0, 0, 0, 0);
#pragma unroll
      for (int i = 0; i < 4; ++i) {
        *reinterpret_cast<ushort4*>(&xn[rrow][cg + i * 4]) = z;
        *reinterpret_cast<ushort4*>(&xn[rrow][64 + cg + i * 4]) = z;
      }
    }
  }
  __syncthreads();
  {
    f32x4 acc[4][4];
#pragma unroll
    for (int m = 0; m < 4; ++m)
#pragma unroll
      for (int n = 0; n < 4; ++n) acc[m][n] = (f32x4){0.f, 0.f, 0.f, 0.f};
#pragma unroll
    for (int ks = 0; ks < 4; ++ks) {
      bf16x8 a[4];
#pragma unroll
      for (int m = 0; m < 4; ++m)
        a[m] = ldL(&xn[m * 16 + arow][ks * 32 + koff]);
#pragma unroll
      for (int n = 0; n < 4; ++n) {
        bf16x8 b = ldA(pnl1, ((wid * 4 + n) * 4 + ks) * 64 + lane);
#pragma unroll
        for (int m = 0; m < 4; ++m) acc[m][n] = mfma16(a[m], b, acc[m][n]);
      }
    }
#pragma unroll
    for (int n = 0; n < 4; ++n) {
      const int col = wid * 64 + n * 16 + arow;
      const float bias = bnl1[col];
#pragma unroll
      for (int m = 0; m < 4; ++m)
#pragma unroll
        for (int r = 0; r < 4; ++r) {
          float v = acc[m][n][r] + bias;
          act[m * 16 + r0 + r][col] = bfr(v > 0.f ? v : 0.f);
        }
    }
  }
  __syncthreads();
  {
    f32x4 acc[4];
#pragma unroll
    for (int n = 0; n < 4; ++n) acc[n] = (f32x4){0.f, 0.f, 0.f, 0.f};
    const int mrow = wid * 16 + arow;
#pragma unroll
    for (int ks = 0; ks < 8; ++ks) {
      bf16x8 a = ldL(&act[mrow][ks * 32 + koff]);
#pragma unroll
      for (int n = 0; n < 4; ++n) {
        bf16x8 b = ldA(pnl2, (n * 8 + ks) * 64 + lane);
        acc[n] = mfma16(a, b, acc[n]);
      }
    }
#pragma unroll
    for (int r = 0; r < 4; ++r) {
      const int row = wid * 16 + r0 + r;
      const int gidx = nb + row;
      if (gidx < NNODES) {
#pragma unroll
        for (int n = 0; n < 4; ++n) {
          const int col = n * 16 + arow;
          out[(size_t)gidx * 64 + col] = bf2f(xn[row][col]) + acc[n][r] + bnl2[col];
        }
      }
    }
  }
}

extern "C" void kernel_launch(void* const* d_in, const int* in_sizes, int n_in,
                              void* d_out, int out_size, void* d_ws, size_t ws_size,
                              hipStream_t stream) {
  const float* hn   = (const float*)d_in[0];
  const float* he   = (const float*)d_in[1];
  const float* fe   = (const float*)d_in[2];
  const float* fes  = (const float*)d_in[3];
  const float* nrm  = (const float*)d_in[4];
  const int*   esrc = (const int*)d_in[5];
  const int*   edst = (const int*)d_in[6];
  const float* w_ev1 = (const float*)d_in[7];  const float* b_ev1 = (const float*)d_in[8];
  const float* w_ev2 = (const float*)d_in[9];  const float* b_ev2 = (const float*)d_in[10];
  const float* w_tp  = (const float*)d_in[11]; const float* b_tp  = (const float*)d_in[12];
  const float* w_eu1 = (const float*)d_in[13]; const float* b_eu1 = (const float*)d_in[14];
  const float* w_eu2 = (const float*)d_in[15]; const float* b_eu2 = (const float*)d_in[16];
  const float* w_nl1 = (const float*)d_in[17]; const float* b_nl1 = (const float*)d_in[18];
  const float* w_nl2 = (const float*)d_in[19]; const float* b_nl2 = (const float*)d_in[20];

  float* out = (float*)d_out;
  char* ws = (char*)d_ws;
  float* nfp = (float*)ws;
  size_t off = (size_t)NNODES * CDIM * sizeof(float);
  unsigned short* pev1 = (unsigned short*)(ws + off); off += (size_t)16 * 6 * 512 * 2;
  unsigned short* peu1 = (unsigned short*)(ws + off); off += (size_t)16 * 6 * 512 * 2;
  unsigned short* pev2 = (unsigned short*)(ws + off); off += (size_t)1 * 8 * 512 * 2;
  unsigned short* peu2 = (unsigned short*)(ws + off); off += (size_t)4 * 8 * 512 * 2;
  unsigned short* ptp  = (unsigned short*)(ws + off); off += (size_t)4 * 2 * 512 * 2;
  unsigned short* pnl1 = (unsigned short*)(ws + off); off += (size_t)16 * 4 * 512 * 2;
  unsigned short* pnl2 = (unsigned short*)(ws + off); off += (size_t)4 * 8 * 512 * 2;

  hipMemsetAsync(nfp, 0, (size_t)NNODES * CDIM * sizeof(float), stream);

  pack_all_kernel<<<84, 256, 0, stream>>>(
      w_ev1, w_eu1, w_nl1, w_eu2, w_nl2, w_ev2, w_tp,
      pev1, peu1, pnl1, peu2, pnl2, pev2, ptp);

  edge_kernel<<<NEDGES / 64, 256, 0, stream>>>(
      hn, he, fe, fes, nrm, esrc, edst,
      pev1, b_ev1, pev2, b_ev2, ptp, b_tp, peu1, b_eu1, peu2, b_eu2,
      out + (size_t)NNODES * CDIM, nfp);

  node_kernel<<<(NNODES + 63) / 64, 256, 0, stream>>>(
      hn, nfp, pnl1, b_nl1, pnl2, b_nl2, out);
}

// Round 8
// 530.659 us; speedup vs baseline: 1.9877x; 1.2577x over previous
//
#include <hip/hip_runtime.h>
#include <hip/hip_bf16.h>
#include <stdint.h>

#define NNODES 50000
#define NEDGES 800000
#define CDIM   64
#define SHD    9
#define EBD    16

using f32x4  = __attribute__((ext_vector_type(4))) float;
using bf16x8 = __attribute__((ext_vector_type(8))) __bf16;

static __device__ __forceinline__ unsigned short f2bf(float x) {
  union { float f; unsigned u; } v; v.f = x;
  unsigned r = (v.u + 0x7FFFu + ((v.u >> 16) & 1u)) >> 16;   // RNE
  return (unsigned short)r;
}
static __device__ __forceinline__ float bf2f(unsigned short b) {
  union { unsigned u; float f; } v; v.u = ((unsigned)b) << 16;
  return v.f;
}
static __device__ __forceinline__ f32x4 mfma16(bf16x8 a, bf16x8 b, f32x4 c) {
  return __builtin_amdgcn_mfma_f32_16x16x32_bf16(a, b, c, 0, 0, 0);
}
// packed bf16 atomic add (global_atomic_pk_add_bf16)
static __device__ __forceinline__ void atomPK(unsigned short* p, float a, float b) {
  union { unsigned short u[2]; __hip_bfloat162 v; } t;
  t.u[0] = f2bf(a); t.u[1] = f2bf(b);
  unsafeAtomicAdd(reinterpret_cast<__hip_bfloat162*>(p), t.v);
}

// One merged pack kernel: fp32 w[K][N] row-major -> bf16 B-fragment order for
// mfma_f32_16x16x32_bf16: dst[((nt*KS+ks)*64 + lane)*8 + j] =
//   w[ks*32 + (lane>>4)*8 + j][nt*16 + (lane&15)], zero-padded OOB.
__global__ void pack_all_kernel(
    const float* __restrict__ wev1, const float* __restrict__ weu1,
    const float* __restrict__ wnl1, const float* __restrict__ weu2,
    const float* __restrict__ wnl2, const float* __restrict__ wev2,
    const float* __restrict__ wtp,
    unsigned short* __restrict__ pev1, unsigned short* __restrict__ peu1,
    unsigned short* __restrict__ pnl1, unsigned short* __restrict__ peu2,
    unsigned short* __restrict__ pnl2, unsigned short* __restrict__ pev2,
    unsigned short* __restrict__ ptp) {
  int b = blockIdx.x;
  const float* w; unsigned short* dst; int K, N, KS, NT, base;
  if (b < 24)      { w = wev1; dst = pev1; K = 192; N = 256; KS = 6; NT = 16; base = 0; }
  else if (b < 48) { w = weu1; dst = peu1; K = 192; N = 256; KS = 6; NT = 16; base = 24; }
  else if (b < 64) { w = wnl1; dst = pnl1; K = 128; N = 256; KS = 4; NT = 16; base = 48; }
  else if (b < 72) { w = weu2; dst = peu2; K = 256; N = 64;  KS = 8; NT = 4;  base = 64; }
  else if (b < 80) { w = wnl2; dst = pnl2; K = 256; N = 64;  KS = 8; NT = 4;  base = 72; }
  else if (b < 82) { w = wev2; dst = pev2; K = 256; N = 9;   KS = 8; NT = 1;  base = 80; }
  else             { w = wtp;  dst = ptp;  K = 34;  N = 64;  KS = 2; NT = 4;  base = 82; }
  int idx = (b - base) * 256 + threadIdx.x;
  int total = NT * KS * 64;
  if (idx >= total) return;
  int lane = idx & 63;
  int t = idx >> 6;
  int ks = t % KS;
  int nt = t / KS;
  int n  = nt * 16 + (lane & 15);
  int kb = ks * 32 + ((lane >> 4) << 3);
  unsigned short v[8];
#pragma unroll
  for (int j = 0; j < 8; ++j) {
    int k = kb + j;
    float val = (k < K && n < N) ? w[(size_t)k * N + n] : 0.f;
    v[j] = f2bf(val);
  }
  uint4 pk;
  pk.x = (unsigned)v[0] | ((unsigned)v[1] << 16);
  pk.y = (unsigned)v[2] | ((unsigned)v[3] << 16);
  pk.z = (unsigned)v[4] | ((unsigned)v[5] << 16);
  pk.w = (unsigned)v[6] | ((unsigned)v[7] << 16);
  reinterpret_cast<uint4*>(dst)[idx] = pk;
}

// Fused per-edge pipeline (R2 structure). 64 edges/block, 4 waves, 3 blocks/CU.
// Epilogue: LDS-transpose (own act rows) -> dwordx4 stores + pk-bf16 atomics.
__global__ __launch_bounds__(256, 3) void edge_kernel(
    const float* __restrict__ hn, const float* __restrict__ he,
    const float* __restrict__ fe, const float* __restrict__ fes,
    const float* __restrict__ nrm,
    const int* __restrict__ esrc, const int* __restrict__ edst,
    const unsigned short* __restrict__ pev1, const float* __restrict__ bev1,
    const unsigned short* __restrict__ pev2, const float* __restrict__ bev2,
    const unsigned short* __restrict__ ptp,  const float* __restrict__ btp,
    const unsigned short* __restrict__ peu1, const float* __restrict__ beu1,
    const unsigned short* __restrict__ peu2, const float* __restrict__ beu2,
    float* __restrict__ out_he, unsigned short* __restrict__ nf) {
  __shared__ unsigned short xa[64][200];   // [he | hs | hd] bf16
  __shared__ unsigned short vt[64][72];    // [v | fe | fes | 0] K-padded to 64; reused for t
  __shared__ unsigned short act[64][136];  // hidden activations, one N-half; epilogue transpose

  const int tid  = threadIdx.x;
  const int lane = tid & 63;
  const int wid  = tid >> 6;
  const int eb   = blockIdx.x * 64;
  const int arow = lane & 15;
  const int koff = (lane >> 4) << 3;
  const int r0   = (lane >> 4) << 2;

  // ---- stage inputs ----
  {
    const int e  = tid >> 2;
    const int q  = tid & 3;
    const int cg = q << 4;
    const int eg = eb + e;
    const int src = esrc[eg];
    const int dst = edst[eg];
    const float4* heP = reinterpret_cast<const float4*>(he + (size_t)eg * 64 + cg);
    const float4* hsP = reinterpret_cast<const float4*>(hn + (size_t)src * 64 + cg);
    const float4* hdP = reinterpret_cast<const float4*>(hn + (size_t)dst * 64 + cg);
#pragma unroll
    for (int i = 0; i < 4; ++i) {
      float4 a = heP[i], b = hsP[i], d = hdP[i];
      *reinterpret_cast<ushort4*>(&xa[e][cg + i * 4]) =
          make_ushort4(f2bf(a.x), f2bf(a.y), f2bf(a.z), f2bf(a.w));
      *reinterpret_cast<ushort4*>(&xa[e][64 + cg + i * 4]) =
          make_ushort4(f2bf(b.x), f2bf(b.y), f2bf(b.z), f2bf(b.w));
      *reinterpret_cast<ushort4*>(&xa[e][128 + cg + i * 4]) =
          make_ushort4(f2bf(d.x), f2bf(d.y), f2bf(d.z), f2bf(d.w));
    }
    // vt: cols 9..17 = fe, 18..33 = fes, 34..63 = 0 (cols 0..8 = v, filled later)
#pragma unroll
    for (int i = 0; i < 16; ++i) {
      int col = cg + i;
      if (col < 9) continue;
      float v = 0.f;
      if (col < 18)      v = fe[(size_t)eg * SHD + (col - 9)];
      else if (col < 34) v = fes[(size_t)eg * EBD + (col - 18)];
      vt[e][col] = f2bf(v);
    }
  }
  __syncthreads();  // S1

  // ---- GEMM1 (two N-halves) interleaved with GEMM2 partial-K accumulation ----
  f32x4 acc2 = (f32x4){0.f, 0.f, 0.f, 0.f};
#pragma unroll
  for (int h = 0; h < 2; ++h) {
    {  // GEMM1 half: a1[:, h*128 : h*128+128] = relu([he|hs|hd] @ w_ev1 + b)
      f32x4 acc[4][2];
#pragma unroll
      for (int m = 0; m < 4; ++m)
#pragma unroll
        for (int n = 0; n < 2; ++n) acc[m][n] = (f32x4){0.f, 0.f, 0.f, 0.f};
#pragma unroll
      for (int ks = 0; ks < 6; ++ks) {
        bf16x8 a[4];
#pragma unroll
        for (int m = 0; m < 4; ++m)
          a[m] = *reinterpret_cast<const bf16x8*>(&xa[m * 16 + arow][ks * 32 + koff]);
#pragma unroll
        for (int n = 0; n < 2; ++n) {
          bf16x8 b = *reinterpret_cast<const bf16x8*>(
              pev1 + (((size_t)(h * 8 + wid * 2 + n) * 6 + ks) * 64 + lane) * 8);
#pragma unroll
          for (int m = 0; m < 4; ++m) acc[m][n] = mfma16(a[m], b, acc[m][n]);
        }
      }
#pragma unroll
      for (int n = 0; n < 2; ++n) {
        const int col_l = wid * 32 + n * 16 + arow;
        const float bias = bev1[h * 128 + col_l];
#pragma unroll
        for (int m = 0; m < 4; ++m)
#pragma unroll
          for (int r = 0; r < 4; ++r) {
            float v = acc[m][n][r] + bias;
            act[m * 16 + r0 + r][col_l] = f2bf(v > 0.f ? v : 0.f);
          }
      }
    }
    __syncthreads();  // S2 / S4
    {  // GEMM2 partial: acc2 += a1_half @ w_ev2_half
      const int mrow = wid * 16 + arow;
#pragma unroll
      for (int ksl = 0; ksl < 4; ++ksl) {
        bf16x8 a = *reinterpret_cast<const bf16x8*>(&act[mrow][ksl * 32 + koff]);
        bf16x8 b = *reinterpret_cast<const bf16x8*>(pev2 + (((size_t)h * 4 + ksl) * 64 + lane) * 8);
        acc2 = mfma16(a, b, acc2);
      }
    }
    if (h == 0) __syncthreads();  // S3 (before half-1 overwrites act)
  }

  // ---- v write (wave-private rows) + GEMM_t (within-wave; vt read-then-overwrite) ----
  if (arow < 9) {
    const float bias = bev2[arow];
#pragma unroll
    for (int r = 0; r < 4; ++r) vt[wid * 16 + r0 + r][arow] = f2bf(acc2[r] + bias);
  }
  {
    f32x4 acct[4];
#pragma unroll
    for (int n = 0; n < 4; ++n) acct[n] = (f32x4){0.f, 0.f, 0.f, 0.f};
    const int mrow = wid * 16 + arow;
#pragma unroll
    for (int ks = 0; ks < 2; ++ks) {
      bf16x8 a = *reinterpret_cast<const bf16x8*>(&vt[mrow][ks * 32 + koff]);
#pragma unroll
      for (int n = 0; n < 4; ++n) {
        bf16x8 b = *reinterpret_cast<const bf16x8*>(ptp + (((size_t)n * 2 + ks) * 64 + lane) * 8);
        acct[n] = mfma16(a, b, acct[n]);
      }
    }
#pragma unroll
    for (int n = 0; n < 4; ++n) {
      const int col = n * 16 + arow;
      const float bias = btp[col];
#pragma unroll
      for (int r = 0; r < 4; ++r) vt[wid * 16 + r0 + r][col] = f2bf(acct[n][r] + bias);
    }
  }
  __syncthreads();  // S5 (t visible to all waves)

  // ---- GEMM3 (two N-halves) interleaved with GEMM4 partial-K accumulation ----
  f32x4 acc4[4];
#pragma unroll
  for (int n = 0; n < 4; ++n) acc4[n] = (f32x4){0.f, 0.f, 0.f, 0.f};
#pragma unroll
  for (int h = 0; h < 2; ++h) {
    {  // GEMM3 half: a2[:, h*128 :] = relu([t|hs|hd] @ w_eu1 + b)
      f32x4 acc[4][2];
#pragma unroll
      for (int m = 0; m < 4; ++m)
#pragma unroll
        for (int n = 0; n < 2; ++n) acc[m][n] = (f32x4){0.f, 0.f, 0.f, 0.f};
#pragma unroll
      for (int ks = 0; ks < 6; ++ks) {
        bf16x8 a[4];
#pragma unroll
        for (int m = 0; m < 4; ++m) {
          if (ks < 2)
            a[m] = *reinterpret_cast<const bf16x8*>(&vt[m * 16 + arow][ks * 32 + koff]);
          else
            a[m] = *reinterpret_cast<const bf16x8*>(&xa[m * 16 + arow][64 + (ks - 2) * 32 + koff]);
        }
#pragma unroll
        for (int n = 0; n < 2; ++n) {
          bf16x8 b = *reinterpret_cast<const bf16x8*>(
              peu1 + (((size_t)(h * 8 + wid * 2 + n) * 6 + ks) * 64 + lane) * 8);
#pragma unroll
          for (int m = 0; m < 4; ++m) acc[m][n] = mfma16(a[m], b, acc[m][n]);
        }
      }
#pragma unroll
      for (int n = 0; n < 2; ++n) {
        const int col_l = wid * 32 + n * 16 + arow;
        const float bias = beu1[h * 128 + col_l];
#pragma unroll
        for (int m = 0; m < 4; ++m)
#pragma unroll
          for (int r = 0; r < 4; ++r) {
            float v = acc[m][n][r] + bias;
            act[m * 16 + r0 + r][col_l] = f2bf(v > 0.f ? v : 0.f);
          }
      }
    }
    __syncthreads();  // S6 / S8
    {  // GEMM4 partial: acc4 += a2_half @ w_eu2_half (reads OWN rows only)
      const int mrow = wid * 16 + arow;
#pragma unroll
      for (int ksl = 0; ksl < 4; ++ksl) {
        bf16x8 a = *reinterpret_cast<const bf16x8*>(&act[mrow][ksl * 32 + koff]);
#pragma unroll
        for (int n = 0; n < 4; ++n) {
          bf16x8 b = *reinterpret_cast<const bf16x8*>(
              peu2 + (((size_t)(n * 8 + h * 4 + ksl)) * 64 + lane) * 8);
          acc4[n] = mfma16(a, b, acc4[n]);
        }
      }
    }
    if (h == 0) __syncthreads();  // S7
  }

  // ---- epilogue: transpose via OWN act rows (race-free: each wave reads/writes
  // only rows wid*16..wid*16+15, LDS ops in-order within a wave), then
  // he_new = he + delta as dwordx4 stores + packed-bf16 atomics ----
  {
    float* tr = reinterpret_cast<float*>(&act[wid * 16][0]);   // 16 rows x 68 f32
#pragma unroll
    for (int n = 0; n < 4; ++n) {
      const float bz = beu2[n * 16 + arow];
#pragma unroll
      for (int r = 0; r < 4; ++r)
        tr[(r0 + r) * 68 + n * 16 + arow] = acc4[n][r] + bz;
    }
    const int j = r0 >> 2;
    const int erow = wid * 16 + arow;      // this thread now owns edge 'erow'
    const int eg = eb + erow;
    const float nv = nrm[eg];
    const int dn = edst[eg];
    unsigned short* nfrow = nf + (size_t)dn * 64;
#pragma unroll
    for (int i = 0; i < 4; ++i) {
      const int c = i * 16 + j * 4;        // contiguous 64B per (row, i) across j
      float4 vv = *reinterpret_cast<const float4*>(&tr[arow * 68 + c]);
      ushort4 hr = *reinterpret_cast<const ushort4*>(&xa[erow][c]);
      vv.x += bf2f(hr.x); vv.y += bf2f(hr.y); vv.z += bf2f(hr.z); vv.w += bf2f(hr.w);
      f32x4 sv = {vv.x, vv.y, vv.z, vv.w};
      __builtin_nontemporal_store(sv, reinterpret_cast<f32x4*>(out_he + (size_t)eg * 64 + c));
      atomPK(nfrow + c + 0, vv.x * nv, vv.y * nv);
      atomPK(nfrow + c + 2, vv.z * nv, vv.w * nv);
    }
  }
}

// Node MLP: hn_new = hn + relu([hn|node_ftr]@w_nl1+b)@w_nl2+b  (nf is bf16 now)
__global__ __launch_bounds__(256, 3) void node_kernel(
    const float* __restrict__ hn, const unsigned short* __restrict__ nf,
    const unsigned short* __restrict__ pnl1, const float* __restrict__ bnl1,
    const unsigned short* __restrict__ pnl2, const float* __restrict__ bnl2,
    float* __restrict__ out) {
  __shared__ unsigned short xn[64][136];   // [hn | node_ftr]
  __shared__ unsigned short act[64][264];
  const int tid = threadIdx.x, lane = tid & 63, wid = tid >> 6;
  const int nb = blockIdx.x * 64;
  const int arow = lane & 15, koff = (lane >> 4) << 3, r0 = (lane >> 4) << 2;
  {
    const int rrow = tid >> 2, q = tid & 3, cg = q << 4;
    const int g = nb + rrow;
    if (g < NNODES) {
      const float4* aP = reinterpret_cast<const float4*>(hn + (size_t)g * 64 + cg);
      const uint4* bP = reinterpret_cast<const uint4*>(nf + (size_t)g * 64 + cg);
#pragma unroll
      for (int i = 0; i < 4; ++i) {
        float4 a = aP[i];
        *reinterpret_cast<ushort4*>(&xn[rrow][cg + i * 4]) =
            make_ushort4(f2bf(a.x), f2bf(a.y), f2bf(a.z), f2bf(a.w));
      }
      *reinterpret_cast<uint4*>(&xn[rrow][64 + cg])     = bP[0];  // raw bf16 copy
      *reinterpret_cast<uint4*>(&xn[rrow][64 + cg + 8]) = bP[1];
    } else {
      ushort4 z = make_ushort4(0, 0, 0, 0);
#pragma unroll
      for (int i = 0; i < 4; ++i) {
        *reinterpret_cast<ushort4*>(&xn[rrow][cg + i * 4]) = z;
        *reinterpret_cast<ushort4*>(&xn[rrow][64 + cg + i * 4]) = z;
      }
    }
  }
  __syncthreads();
  {
    f32x4 acc[4][4];
#pragma unroll
    for (int m = 0; m < 4; ++m)
#pragma unroll
      for (int n = 0; n < 4; ++n) acc[m][n] = (f32x4){0.f, 0.f, 0.f, 0.f};
#pragma unroll
    for (int ks = 0; ks < 4; ++ks) {
      bf16x8 a[4];
#pragma unroll
      for (int m = 0; m < 4; ++m)
        a[m] = *reinterpret_cast<const bf16x8*>(&xn[m * 16 + arow][ks * 32 + koff]);
#pragma unroll
      for (int n = 0; n < 4; ++n) {
        bf16x8 b = *reinterpret_cast<const bf16x8*>(
            pnl1 + (((size_t)(wid * 4 + n) * 4 + ks) * 64 + lane) * 8);
#pragma unroll
        for (int m = 0; m < 4; ++m) acc[m][n] = mfma16(a[m], b, acc[m][n]);
      }
    }
#pragma unroll
    for (int n = 0; n < 4; ++n) {
      const int col = wid * 64 + n * 16 + arow;
      const float bias = bnl1[col];
#pragma unroll
      for (int m = 0; m < 4; ++m)
#pragma unroll
        for (int r = 0; r < 4; ++r) {
          float v = acc[m][n][r] + bias;
          act[m * 16 + r0 + r][col] = f2bf(v > 0.f ? v : 0.f);
        }
    }
  }
  __syncthreads();
  {
    f32x4 acc[4];
#pragma unroll
    for (int n = 0; n < 4; ++n) acc[n] = (f32x4){0.f, 0.f, 0.f, 0.f};
    const int mrow = wid * 16 + arow;
#pragma unroll
    for (int ks = 0; ks < 8; ++ks) {
      bf16x8 a = *reinterpret_cast<const bf16x8*>(&act[mrow][ks * 32 + koff]);
#pragma unroll
      for (int n = 0; n < 4; ++n) {
        bf16x8 b = *reinterpret_cast<const bf16x8*>(pnl2 + (((size_t)n * 8 + ks) * 64 + lane) * 8);
        acc[n] = mfma16(a, b, acc[n]);
      }
    }
#pragma unroll
    for (int r = 0; r < 4; ++r) {
      const int row = wid * 16 + r0 + r;
      const int g = nb + row;
      if (g < NNODES) {
#pragma unroll
        for (int n = 0; n < 4; ++n) {
          const int col = n * 16 + arow;
          out[(size_t)g * 64 + col] = bf2f(xn[row][col]) + acc[n][r] + bnl2[col];
        }
      }
    }
  }
}

extern "C" void kernel_launch(void* const* d_in, const int* in_sizes, int n_in,
                              void* d_out, int out_size, void* d_ws, size_t ws_size,
                              hipStream_t stream) {
  const float* hn   = (const float*)d_in[0];
  const float* he   = (const float*)d_in[1];
  const float* fe   = (const float*)d_in[2];
  const float* fes  = (const float*)d_in[3];
  const float* nrm  = (const float*)d_in[4];
  const int*   esrc = (const int*)d_in[5];
  const int*   edst = (const int*)d_in[6];
  const float* w_ev1 = (const float*)d_in[7];  const float* b_ev1 = (const float*)d_in[8];
  const float* w_ev2 = (const float*)d_in[9];  const float* b_ev2 = (const float*)d_in[10];
  const float* w_tp  = (const float*)d_in[11]; const float* b_tp  = (const float*)d_in[12];
  const float* w_eu1 = (const float*)d_in[13]; const float* b_eu1 = (const float*)d_in[14];
  const float* w_eu2 = (const float*)d_in[15]; const float* b_eu2 = (const float*)d_in[16];
  const float* w_nl1 = (const float*)d_in[17]; const float* b_nl1 = (const float*)d_in[18];
  const float* w_nl2 = (const float*)d_in[19]; const float* b_nl2 = (const float*)d_in[20];

  float* out = (float*)d_out;
  char* ws = (char*)d_ws;
  unsigned short* nfp = (unsigned short*)ws;                 // node_ftr accumulator [N,64] bf16
  size_t off = (size_t)NNODES * CDIM * sizeof(unsigned short);
  unsigned short* pev1 = (unsigned short*)(ws + off); off += (size_t)16 * 6 * 512 * 2;
  unsigned short* peu1 = (unsigned short*)(ws + off); off += (size_t)16 * 6 * 512 * 2;
  unsigned short* pev2 = (unsigned short*)(ws + off); off += (size_t)1 * 8 * 512 * 2;
  unsigned short* peu2 = (unsigned short*)(ws + off); off += (size_t)4 * 8 * 512 * 2;
  unsigned short* ptp  = (unsigned short*)(ws + off); off += (size_t)4 * 2 * 512 * 2;
  unsigned short* pnl1 = (unsigned short*)(ws + off); off += (size_t)16 * 4 * 512 * 2;
  unsigned short* pnl2 = (unsigned short*)(ws + off); off += (size_t)4 * 8 * 512 * 2;

  hipMemsetAsync(nfp, 0, (size_t)NNODES * CDIM * sizeof(unsigned short), stream);

  pack_all_kernel<<<84, 256, 0, stream>>>(
      w_ev1, w_eu1, w_nl1, w_eu2, w_nl2, w_ev2, w_tp,
      pev1, peu1, pnl1, peu2, pnl2, pev2, ptp);

  edge_kernel<<<NEDGES / 64, 256, 0, stream>>>(
      hn, he, fe, fes, nrm, esrc, edst,
      pev1, b_ev1, pev2, b_ev2, ptp, b_tp, peu1, b_eu1, peu2, b_eu2,
      out + (size_t)NNODES * CDIM, nfp);

  node_kernel<<<(NNODES + 63) / 64, 256, 0, stream>>>(
      hn, nfp, pnl1, b_nl1, pnl2, b_nl2, out);
}

// Round 9
// 521.277 us; speedup vs baseline: 2.0235x; 1.0180x over previous
//
#include <hip/hip_runtime.h>
#include <hip/hip_bf16.h>
#include <stdint.h>

#define NNODES 50000
#define NEDGES 800000
#define CDIM   64
#define SHD    9
#define EBD    16

using f32x4  = __attribute__((ext_vector_type(4))) float;
using bf16x8 = __attribute__((ext_vector_type(8))) __bf16;

static __device__ __forceinline__ unsigned short f2bf(float x) {
  union { float f; unsigned u; } v; v.f = x;
  unsigned r = (v.u + 0x7FFFu + ((v.u >> 16) & 1u)) >> 16;   // RNE
  return (unsigned short)r;
}
static __device__ __forceinline__ float bf2f(unsigned short b) {
  union { unsigned u; float f; } v; v.u = ((unsigned)b) << 16;
  return v.f;
}
static __device__ __forceinline__ f32x4 mfma16(bf16x8 a, bf16x8 b, f32x4 c) {
  return __builtin_amdgcn_mfma_f32_16x16x32_bf16(a, b, c, 0, 0, 0);
}
// packed bf16 atomic add (global_atomic_pk_add_bf16)
static __device__ __forceinline__ void atomPK(unsigned short* p, float a, float b) {
  union { unsigned short u[2]; __hip_bfloat162 v; } t;
  t.u[0] = f2bf(a); t.u[1] = f2bf(b);
  unsafeAtomicAdd(reinterpret_cast<__hip_bfloat162*>(p), t.v);
}

// One merged pack kernel: fp32 w[K][N] row-major -> bf16 B-fragment order for
// mfma_f32_16x16x32_bf16: dst[((nt*KS+ks)*64 + lane)*8 + j] =
//   w[ks*32 + (lane>>4)*8 + j][nt*16 + (lane&15)], zero-padded OOB.
__global__ void pack_all_kernel(
    const float* __restrict__ wev1, const float* __restrict__ weu1,
    const float* __restrict__ wnl1, const float* __restrict__ weu2,
    const float* __restrict__ wnl2, const float* __restrict__ wev2,
    const float* __restrict__ wtp,
    unsigned short* __restrict__ pev1, unsigned short* __restrict__ peu1,
    unsigned short* __restrict__ pnl1, unsigned short* __restrict__ peu2,
    unsigned short* __restrict__ pnl2, unsigned short* __restrict__ pev2,
    unsigned short* __restrict__ ptp) {
  int b = blockIdx.x;
  const float* w; unsigned short* dst; int K, N, KS, NT, base;
  if (b < 24)      { w = wev1; dst = pev1; K = 192; N = 256; KS = 6; NT = 16; base = 0; }
  else if (b < 48) { w = weu1; dst = peu1; K = 192; N = 256; KS = 6; NT = 16; base = 24; }
  else if (b < 64) { w = wnl1; dst = pnl1; K = 128; N = 256; KS = 4; NT = 16; base = 48; }
  else if (b < 72) { w = weu2; dst = peu2; K = 256; N = 64;  KS = 8; NT = 4;  base = 64; }
  else if (b < 80) { w = wnl2; dst = pnl2; K = 256; N = 64;  KS = 8; NT = 4;  base = 72; }
  else if (b < 82) { w = wev2; dst = pev2; K = 256; N = 9;   KS = 8; NT = 1;  base = 80; }
  else             { w = wtp;  dst = ptp;  K = 34;  N = 64;  KS = 2; NT = 4;  base = 82; }
  int idx = (b - base) * 256 + threadIdx.x;
  int total = NT * KS * 64;
  if (idx >= total) return;
  int lane = idx & 63;
  int t = idx >> 6;
  int ks = t % KS;
  int nt = t / KS;
  int n  = nt * 16 + (lane & 15);
  int kb = ks * 32 + ((lane >> 4) << 3);
  unsigned short v[8];
#pragma unroll
  for (int j = 0; j < 8; ++j) {
    int k = kb + j;
    float val = (k < K && n < N) ? w[(size_t)k * N + n] : 0.f;
    v[j] = f2bf(val);
  }
  uint4 pk;
  pk.x = (unsigned)v[0] | ((unsigned)v[1] << 16);
  pk.y = (unsigned)v[2] | ((unsigned)v[3] << 16);
  pk.z = (unsigned)v[4] | ((unsigned)v[5] << 16);
  pk.w = (unsigned)v[6] | ((unsigned)v[7] << 16);
  reinterpret_cast<uint4*>(dst)[idx] = pk;
}

// Fused per-edge pipeline (R2 structure). 64 edges/block, 4 waves, 3 blocks/CU.
// Epilogue: LDS-transpose (own act rows) -> dwordx4 stores + pk-bf16 atomics.
__global__ __launch_bounds__(256, 3) void edge_kernel(
    const float* __restrict__ hn, const float* __restrict__ he,
    const float* __restrict__ fe, const float* __restrict__ fes,
    const float* __restrict__ nrm,
    const int* __restrict__ esrc, const int* __restrict__ edst,
    const unsigned short* __restrict__ pev1, const float* __restrict__ bev1,
    const unsigned short* __restrict__ pev2, const float* __restrict__ bev2,
    const unsigned short* __restrict__ ptp,  const float* __restrict__ btp,
    const unsigned short* __restrict__ peu1, const float* __restrict__ beu1,
    const unsigned short* __restrict__ peu2, const float* __restrict__ beu2,
    float* __restrict__ out_he, unsigned short* __restrict__ nf) {
  __shared__ unsigned short xa[64][200];   // [he | hs | hd] bf16
  __shared__ unsigned short vt[64][72];    // [v | fe | fes | 0] K-padded to 64; reused for t
  __shared__ unsigned short act[64][136];  // hidden activations, one N-half; epilogue transpose

  const int tid  = threadIdx.x;
  const int lane = tid & 63;
  const int wid  = tid >> 6;
  const int eb   = blockIdx.x * 64;
  const int arow = lane & 15;
  const int koff = (lane >> 4) << 3;
  const int r0   = (lane >> 4) << 2;

  // ---- stage inputs ----
  {
    const int e  = tid >> 2;
    const int q  = tid & 3;
    const int cg = q << 4;
    const int eg = eb + e;
    const int src = esrc[eg];
    const int dst = edst[eg];
    const float4* heP = reinterpret_cast<const float4*>(he + (size_t)eg * 64 + cg);
    const float4* hsP = reinterpret_cast<const float4*>(hn + (size_t)src * 64 + cg);
    const float4* hdP = reinterpret_cast<const float4*>(hn + (size_t)dst * 64 + cg);
#pragma unroll
    for (int i = 0; i < 4; ++i) {
      float4 a = heP[i], b = hsP[i], d = hdP[i];
      *reinterpret_cast<ushort4*>(&xa[e][cg + i * 4]) =
          make_ushort4(f2bf(a.x), f2bf(a.y), f2bf(a.z), f2bf(a.w));
      *reinterpret_cast<ushort4*>(&xa[e][64 + cg + i * 4]) =
          make_ushort4(f2bf(b.x), f2bf(b.y), f2bf(b.z), f2bf(b.w));
      *reinterpret_cast<ushort4*>(&xa[e][128 + cg + i * 4]) =
          make_ushort4(f2bf(d.x), f2bf(d.y), f2bf(d.z), f2bf(d.w));
    }
    // vt: cols 9..17 = fe, 18..33 = fes, 34..63 = 0 (cols 0..8 = v, filled later)
#pragma unroll
    for (int i = 0; i < 16; ++i) {
      int col = cg + i;
      if (col < 9) continue;
      float v = 0.f;
      if (col < 18)      v = fe[(size_t)eg * SHD + (col - 9)];
      else if (col < 34) v = fes[(size_t)eg * EBD + (col - 18)];
      vt[e][col] = f2bf(v);
    }
  }
  __syncthreads();  // S1

  // ---- GEMM1 (two N-halves) interleaved with GEMM2 partial-K accumulation ----
  f32x4 acc2 = (f32x4){0.f, 0.f, 0.f, 0.f};
#pragma unroll
  for (int h = 0; h < 2; ++h) {
    {  // GEMM1 half: a1[:, h*128 : h*128+128] = relu([he|hs|hd] @ w_ev1 + b)
      f32x4 acc[4][2];
#pragma unroll
      for (int m = 0; m < 4; ++m)
#pragma unroll
        for (int n = 0; n < 2; ++n) acc[m][n] = (f32x4){0.f, 0.f, 0.f, 0.f};
#pragma unroll
      for (int ks = 0; ks < 6; ++ks) {
        bf16x8 a[4];
#pragma unroll
        for (int m = 0; m < 4; ++m)
          a[m] = *reinterpret_cast<const bf16x8*>(&xa[m * 16 + arow][ks * 32 + koff]);
#pragma unroll
        for (int n = 0; n < 2; ++n) {
          bf16x8 b = *reinterpret_cast<const bf16x8*>(
              pev1 + (((size_t)(h * 8 + wid * 2 + n) * 6 + ks) * 64 + lane) * 8);
#pragma unroll
          for (int m = 0; m < 4; ++m) acc[m][n] = mfma16(a[m], b, acc[m][n]);
        }
      }
#pragma unroll
      for (int n = 0; n < 2; ++n) {
        const int col_l = wid * 32 + n * 16 + arow;
        const float bias = bev1[h * 128 + col_l];
#pragma unroll
        for (int m = 0; m < 4; ++m)
#pragma unroll
          for (int r = 0; r < 4; ++r) {
            float v = acc[m][n][r] + bias;
            act[m * 16 + r0 + r][col_l] = f2bf(v > 0.f ? v : 0.f);
          }
      }
    }
    __syncthreads();  // S2 / S4
    {  // GEMM2 partial: acc2 += a1_half @ w_ev2_half
      const int mrow = wid * 16 + arow;
#pragma unroll
      for (int ksl = 0; ksl < 4; ++ksl) {
        bf16x8 a = *reinterpret_cast<const bf16x8*>(&act[mrow][ksl * 32 + koff]);
        bf16x8 b = *reinterpret_cast<const bf16x8*>(pev2 + (((size_t)h * 4 + ksl) * 64 + lane) * 8);
        acc2 = mfma16(a, b, acc2);
      }
    }
    if (h == 0) __syncthreads();  // S3 (before half-1 overwrites act)
  }

  // ---- v write (wave-private rows) + GEMM_t (within-wave; vt read-then-overwrite) ----
  if (arow < 9) {
    const float bias = bev2[arow];
#pragma unroll
    for (int r = 0; r < 4; ++r) vt[wid * 16 + r0 + r][arow] = f2bf(acc2[r] + bias);
  }
  {
    f32x4 acct[4];
#pragma unroll
    for (int n = 0; n < 4; ++n) acct[n] = (f32x4){0.f, 0.f, 0.f, 0.f};
    const int mrow = wid * 16 + arow;
#pragma unroll
    for (int ks = 0; ks < 2; ++ks) {
      bf16x8 a = *reinterpret_cast<const bf16x8*>(&vt[mrow][ks * 32 + koff]);
#pragma unroll
      for (int n = 0; n < 4; ++n) {
        bf16x8 b = *reinterpret_cast<const bf16x8*>(ptp + (((size_t)n * 2 + ks) * 64 + lane) * 8);
        acct[n] = mfma16(a, b, acct[n]);
      }
    }
#pragma unroll
    for (int n = 0; n < 4; ++n) {
      const int col = n * 16 + arow;
      const float bias = btp[col];
#pragma unroll
      for (int r = 0; r < 4; ++r) vt[wid * 16 + r0 + r][col] = f2bf(acct[n][r] + bias);
    }
  }
  __syncthreads();  // S5 (t visible to all waves)

  // ---- GEMM3 (two N-halves) interleaved with GEMM4 partial-K accumulation ----
  f32x4 acc4[4];
#pragma unroll
  for (int n = 0; n < 4; ++n) acc4[n] = (f32x4){0.f, 0.f, 0.f, 0.f};
#pragma unroll
  for (int h = 0; h < 2; ++h) {
    {  // GEMM3 half: a2[:, h*128 :] = relu([t|hs|hd] @ w_eu1 + b)
      f32x4 acc[4][2];
#pragma unroll
      for (int m = 0; m < 4; ++m)
#pragma unroll
        for (int n = 0; n < 2; ++n) acc[m][n] = (f32x4){0.f, 0.f, 0.f, 0.f};
#pragma unroll
      for (int ks = 0; ks < 6; ++ks) {
        bf16x8 a[4];
#pragma unroll
        for (int m = 0; m < 4; ++m) {
          if (ks < 2)
            a[m] = *reinterpret_cast<const bf16x8*>(&vt[m * 16 + arow][ks * 32 + koff]);
          else
            a[m] = *reinterpret_cast<const bf16x8*>(&xa[m * 16 + arow][64 + (ks - 2) * 32 + koff]);
        }
#pragma unroll
        for (int n = 0; n < 2; ++n) {
          bf16x8 b = *reinterpret_cast<const bf16x8*>(
              peu1 + (((size_t)(h * 8 + wid * 2 + n) * 6 + ks) * 64 + lane) * 8);
#pragma unroll
          for (int m = 0; m < 4; ++m) acc[m][n] = mfma16(a[m], b, acc[m][n]);
        }
      }
#pragma unroll
      for (int n = 0; n < 2; ++n) {
        const int col_l = wid * 32 + n * 16 + arow;
        const float bias = beu1[h * 128 + col_l];
#pragma unroll
        for (int m = 0; m < 4; ++m)
#pragma unroll
          for (int r = 0; r < 4; ++r) {
            float v = acc[m][n][r] + bias;
            act[m * 16 + r0 + r][col_l] = f2bf(v > 0.f ? v : 0.f);
          }
      }
    }
    __syncthreads();  // S6 / S8
    {  // GEMM4 partial: acc4 += a2_half @ w_eu2_half (reads OWN rows only)
      const int mrow = wid * 16 + arow;
#pragma unroll
      for (int ksl = 0; ksl < 4; ++ksl) {
        bf16x8 a = *reinterpret_cast<const bf16x8*>(&act[mrow][ksl * 32 + koff]);
#pragma unroll
        for (int n = 0; n < 4; ++n) {
          bf16x8 b = *reinterpret_cast<const bf16x8*>(
              peu2 + (((size_t)(n * 8 + h * 4 + ksl)) * 64 + lane) * 8);
          acc4[n] = mfma16(a, b, acc4[n]);
        }
      }
    }
    if (h == 0) __syncthreads();  // S7
  }

  // ---- epilogue: transpose via OWN act rows (race-free: each wave reads/writes
  // only rows wid*16..wid*16+15, LDS ops in-order within a wave), then
  // he_new = he + delta as dwordx4 stores + packed-bf16 atomics ----
  {
    float* tr = reinterpret_cast<float*>(&act[wid * 16][0]);   // 16 rows x 68 f32
#pragma unroll
    for (int n = 0; n < 4; ++n) {
      const float bz = beu2[n * 16 + arow];
#pragma unroll
      for (int r = 0; r < 4; ++r)
        tr[(r0 + r) * 68 + n * 16 + arow] = acc4[n][r] + bz;
    }
    const int j = r0 >> 2;
    const int erow = wid * 16 + arow;      // this thread now owns edge 'erow'
    const int eg = eb + erow;
    const float nv = nrm[eg];
    const int dn = edst[eg];
    unsigned short* nfrow = nf + (size_t)dn * 64;
#pragma unroll
    for (int i = 0; i < 4; ++i) {
      const int c = i * 16 + j * 4;        // contiguous 64B per (row, i) across j
      float4 vv = *reinterpret_cast<const float4*>(&tr[arow * 68 + c]);
      ushort4 hr = *reinterpret_cast<const ushort4*>(&xa[erow][c]);
      vv.x += bf2f(hr.x); vv.y += bf2f(hr.y); vv.z += bf2f(hr.z); vv.w += bf2f(hr.w);
      *reinterpret_cast<float4*>(out_he + (size_t)eg * 64 + c) = vv;   // plain store: L2 coalesces
      atomPK(nfrow + c + 0, vv.x * nv, vv.y * nv);
      atomPK(nfrow + c + 2, vv.z * nv, vv.w * nv);
    }
  }
}

// Node MLP: hn_new = hn + relu([hn|node_ftr]@w_nl1+b)@w_nl2+b  (nf is bf16)
__global__ __launch_bounds__(256, 3) void node_kernel(
    const float* __restrict__ hn, const unsigned short* __restrict__ nf,
    const unsigned short* __restrict__ pnl1, const float* __restrict__ bnl1,
    const unsigned short* __restrict__ pnl2, const float* __restrict__ bnl2,
    float* __restrict__ out) {
  __shared__ unsigned short xn[64][136];   // [hn | node_ftr]
  __shared__ unsigned short act[64][264];
  const int tid = threadIdx.x, lane = tid & 63, wid = tid >> 6;
  const int nb = blockIdx.x * 64;
  const int arow = lane & 15, koff = (lane >> 4) << 3, r0 = (lane >> 4) << 2;
  {
    const int rrow = tid >> 2, q = tid & 3, cg = q << 4;
    const int g = nb + rrow;
    if (g < NNODES) {
      const float4* aP = reinterpret_cast<const float4*>(hn + (size_t)g * 64 + cg);
      const uint4* bP = reinterpret_cast<const uint4*>(nf + (size_t)g * 64 + cg);
#pragma unroll
      for (int i = 0; i < 4; ++i) {
        float4 a = aP[i];
        *reinterpret_cast<ushort4*>(&xn[rrow][cg + i * 4]) =
            make_ushort4(f2bf(a.x), f2bf(a.y), f2bf(a.z), f2bf(a.w));
      }
      *reinterpret_cast<uint4*>(&xn[rrow][64 + cg])     = bP[0];  // raw bf16 copy
      *reinterpret_cast<uint4*>(&xn[rrow][64 + cg + 8]) = bP[1];
    } else {
      ushort4 z = make_ushort4(0, 0, 0, 0);
#pragma unroll
      for (int i = 0; i < 4; ++i) {
        *reinterpret_cast<ushort4*>(&xn[rrow][cg + i * 4]) = z;
        *reinterpret_cast<ushort4*>(&xn[rrow][64 + cg + i * 4]) = z;
      }
    }
  }
  __syncthreads();
  {
    f32x4 acc[4][4];
#pragma unroll
    for (int m = 0; m < 4; ++m)
#pragma unroll
      for (int n = 0; n < 4; ++n) acc[m][n] = (f32x4){0.f, 0.f, 0.f, 0.f};
#pragma unroll
    for (int ks = 0; ks < 4; ++ks) {
      bf16x8 a[4];
#pragma unroll
      for (int m = 0; m < 4; ++m)
        a[m] = *reinterpret_cast<const bf16x8*>(&xn[m * 16 + arow][ks * 32 + koff]);
#pragma unroll
      for (int n = 0; n < 4; ++n) {
        bf16x8 b = *reinterpret_cast<const bf16x8*>(
            pnl1 + (((size_t)(wid * 4 + n) * 4 + ks) * 64 + lane) * 8);
#pragma unroll
        for (int m = 0; m < 4; ++m) acc[m][n] = mfma16(a[m], b, acc[m][n]);
      }
    }
#pragma unroll
    for (int n = 0; n < 4; ++n) {
      const int col = wid * 64 + n * 16 + arow;
      const float bias = bnl1[col];
#pragma unroll
      for (int m = 0; m < 4; ++m)
#pragma unroll
        for (int r = 0; r < 4; ++r) {
          float v = acc[m][n][r] + bias;
          act[m * 16 + r0 + r][col] = f2bf(v > 0.f ? v : 0.f);
        }
    }
  }
  __syncthreads();
  {
    f32x4 acc[4];
#pragma unroll
    for (int n = 0; n < 4; ++n) acc[n] = (f32x4){0.f, 0.f, 0.f, 0.f};
    const int mrow = wid * 16 + arow;
#pragma unroll
    for (int ks = 0; ks < 8; ++ks) {
      bf16x8 a = *reinterpret_cast<const bf16x8*>(&act[mrow][ks * 32 + koff]);
#pragma unroll
      for (int n = 0; n < 4; ++n) {
        bf16x8 b = *reinterpret_cast<const bf16x8*>(pnl2 + (((size_t)n * 8 + ks) * 64 + lane) * 8);
        acc[n] = mfma16(a, b, acc[n]);
      }
    }
#pragma unroll
    for (int r = 0; r < 4; ++r) {
      const int row = wid * 16 + r0 + r;
      const int g = nb + row;
      if (g < NNODES) {
#pragma unroll
        for (int n = 0; n < 4; ++n) {
          const int col = n * 16 + arow;
          out[(size_t)g * 64 + col] = bf2f(xn[row][col]) + acc[n][r] + bnl2[col];
        }
      }
    }
  }
}

extern "C" void kernel_launch(void* const* d_in, const int* in_sizes, int n_in,
                              void* d_out, int out_size, void* d_ws, size_t ws_size,
                              hipStream_t stream) {
  const float* hn   = (const float*)d_in[0];
  const float* he   = (const float*)d_in[1];
  const float* fe   = (const float*)d_in[2];
  const float* fes  = (const float*)d_in[3];
  const float* nrm  = (const float*)d_in[4];
  const int*   esrc = (const int*)d_in[5];
  const int*   edst = (const int*)d_in[6];
  const float* w_ev1 = (const float*)d_in[7];  const float* b_ev1 = (const float*)d_in[8];
  const float* w_ev2 = (const float*)d_in[9];  const float* b_ev2 = (const float*)d_in[10];
  const float* w_tp  = (const float*)d_in[11]; const float* b_tp  = (const float*)d_in[12];
  const float* w_eu1 = (const float*)d_in[13]; const float* b_eu1 = (const float*)d_in[14];
  const float* w_eu2 = (const float*)d_in[15]; const float* b_eu2 = (const float*)d_in[16];
  const float* w_nl1 = (const float*)d_in[17]; const float* b_nl1 = (const float*)d_in[18];
  const float* w_nl2 = (const float*)d_in[19]; const float* b_nl2 = (const float*)d_in[20];

  float* out = (float*)d_out;
  char* ws = (char*)d_ws;
  unsigned short* nfp = (unsigned short*)ws;                 // node_ftr accumulator [N,64] bf16
  size_t off = (size_t)NNODES * CDIM * sizeof(unsigned short);
  unsigned short* pev1 = (unsigned short*)(ws + off); off += (size_t)16 * 6 * 512 * 2;
  unsigned short* peu1 = (unsigned short*)(ws + off); off += (size_t)16 * 6 * 512 * 2;
  unsigned short* pev2 = (unsigned short*)(ws + off); off += (size_t)1 * 8 * 512 * 2;
  unsigned short* peu2 = (unsigned short*)(ws + off); off += (size_t)4 * 8 * 512 * 2;
  unsigned short* ptp  = (unsigned short*)(ws + off); off += (size_t)4 * 2 * 512 * 2;
  unsigned short* pnl1 = (unsigned short*)(ws + off); off += (size_t)16 * 4 * 512 * 2;
  unsigned short* pnl2 = (unsigned short*)(ws + off); off += (size_t)4 * 8 * 512 * 2;

  hipMemsetAsync(nfp, 0, (size_t)NNODES * CDIM * sizeof(unsigned short), stream);

  pack_all_kernel<<<84, 256, 0, stream>>>(
      w_ev1, w_eu1, w_nl1, w_eu2, w_nl2, w_ev2, w_tp,
      pev1, peu1, pnl1, peu2, pnl2, pev2, ptp);

  edge_kernel<<<NEDGES / 64, 256, 0, stream>>>(
      hn, he, fe, fes, nrm, esrc, edst,
      pev1, b_ev1, pev2, b_ev2, ptp, b_tp, peu1, b_eu1, peu2, b_eu2,
      out + (size_t)NNODES * CDIM, nfp);

  node_kernel<<<(NNODES + 63) / 64, 256, 0, stream>>>(
      hn, nfp, pnl1, b_nl1, pnl2, b_nl2, out);
}